// Round 1
// 1471.027 us; speedup vs baseline: 1.4614x; 1.4614x over previous
//
#include <hip/hip_runtime.h>

#define N_USERS 100000
#define N_ITEMS 200000
#define N_NODES 300000
#define EMB 64
#define NNZ_C 9600000

#define RPB 256                      // rows per bucket
#define NB 1172                      // ceil(300000 / 256)
#define NB2 2048                     // NB padded to 2*1024 for the scan
#define P1_CHUNK 9375                // 256 blocks * 4 chunks * 9375 = 9.6M exactly
#define P2_CHUNK 4096

// ==================== elementwise ====================

__global__ void init_kernel(const float4* __restrict__ ue, const float4* __restrict__ ie,
                            float4* __restrict__ ego, float4* __restrict__ acc) {
    const int user4 = N_USERS * EMB / 4;
    const int total4 = N_NODES * EMB / 4;
    int stride = gridDim.x * blockDim.x;
    for (int i = blockIdx.x * blockDim.x + threadIdx.x; i < total4; i += stride) {
        float4 v = (i < user4) ? ue[i] : ie[i - user4];
        ego[i] = v;
        acc[i] = v;
    }
}

__global__ void zero_int_kernel(int* __restrict__ p, int n) {
    int stride = gridDim.x * blockDim.x;
    for (int i = blockIdx.x * blockDim.x + threadIdx.x; i < n; i += stride) p[i] = 0;
}

// ==================== bucket histogram (LDS-binned) ====================

__global__ __launch_bounds__(1024) void bhist_kernel(const int* __restrict__ rows,
                                                     int* __restrict__ bcounts) {
    __shared__ int lh[NB];
    for (int i = threadIdx.x; i < NB; i += 1024) lh[i] = 0;
    __syncthreads();
    int stride = gridDim.x * blockDim.x;
    for (int e = blockIdx.x * blockDim.x + threadIdx.x; e < NNZ_C; e += stride)
        atomicAdd(&lh[rows[e] >> 8], 1);
    __syncthreads();
    for (int i = threadIdx.x; i < NB; i += 1024)
        if (lh[i]) atomicAdd(&bcounts[i], lh[i]);
}

// exclusive scan of 1172 bucket counts, single block (2 elems/thread)
__global__ __launch_bounds__(1024) void bscan_kernel(const int* __restrict__ bcounts,
                                                     int* __restrict__ bbase,
                                                     int* __restrict__ bcursor) {
    __shared__ int ts[1024];
    int t = threadIdx.x;
    int c0 = (2 * t < NB) ? bcounts[2 * t] : 0;
    int c1 = (2 * t + 1 < NB) ? bcounts[2 * t + 1] : 0;
    int s = c0 + c1;
    ts[t] = s;
    __syncthreads();
    for (int off = 1; off < 1024; off <<= 1) {
        int v = (t >= off) ? ts[t - off] : 0;
        __syncthreads();
        ts[t] += v;
        __syncthreads();
    }
    int excl = ts[t] - s;
    if (2 * t < NB)     { bbase[2 * t] = excl;          bcursor[2 * t] = excl; }
    if (2 * t + 1 < NB) { bbase[2 * t + 1] = excl + c0; bcursor[2 * t + 1] = excl + c0; }
    if (t == 0) bbase[NB] = NNZ_C;
}

// ==================== pass 1: LDS multi-split into bucket-major order ====================
// entry: x = (rowlow<<19)|col (col<2^19, rowlow<2^8), y = val bits

__global__ __launch_bounds__(1024) void bin_kernel(const int* __restrict__ rows,
                                                   const int* __restrict__ cols,
                                                   const float* __restrict__ vals,
                                                   int* __restrict__ bcursor,
                                                   uint2* __restrict__ cvt) {
    __shared__ int lh[NB2];
    __shared__ int lb[NB2];
    __shared__ int gb[NB];
    __shared__ int ts[1024];
    __shared__ uint2 stg[P1_CHUNK];            // 75 KB
    __shared__ unsigned short sbk[P1_CHUNK];   // 18.3 KB
    int tid = threadIdx.x;
    for (int c = 0; c < 4; ++c) {
        int cb = (blockIdx.x * 4 + c) * P1_CHUNK;
        lh[tid] = 0;
        lh[tid + 1024] = 0;
        __syncthreads();
        int ebr[10]; int epk[10]; float evl[10];
        #pragma unroll
        for (int j = 0; j < 10; ++j) {
            int i = j * 1024 + tid;
            ebr[j] = -1;
            if (i < P1_CHUNK) {
                int e = cb + i;
                int r = rows[e];
                int cc = cols[e];
                float v = vals[e];
                int bk = r >> 8;
                int rk = atomicAdd(&lh[bk], 1);       // rk < 9375 < 2^14
                ebr[j] = (bk << 14) | rk;
                epk[j] = ((r & 255) << 19) | cc;
                evl[j] = v;
            }
        }
        __syncthreads();
        // scan lh[0..2047] -> lb (exclusive), reserve global space per bucket
        int c0 = lh[2 * tid], c1 = lh[2 * tid + 1];
        int s = c0 + c1;
        ts[tid] = s;
        __syncthreads();
        for (int off = 1; off < 1024; off <<= 1) {
            int v = (tid >= off) ? ts[tid - off] : 0;
            __syncthreads();
            ts[tid] += v;
            __syncthreads();
        }
        int excl = ts[tid] - s;
        lb[2 * tid] = excl;
        lb[2 * tid + 1] = excl + c0;
        if (2 * tid < NB && c0)     gb[2 * tid]     = atomicAdd(&bcursor[2 * tid], c0);
        if (2 * tid + 1 < NB && c1) gb[2 * tid + 1] = atomicAdd(&bcursor[2 * tid + 1], c1);
        __syncthreads();
        // stage grouped by bucket
        #pragma unroll
        for (int j = 0; j < 10; ++j) {
            if (ebr[j] >= 0) {
                int bk = ebr[j] >> 14, rk = ebr[j] & 16383;
                int idx = lb[bk] + rk;
                stg[idx] = make_uint2((unsigned)epk[j], __float_as_uint(evl[j]));
                sbk[idx] = (unsigned short)bk;
            }
        }
        __syncthreads();
        // write out: consecutive lanes -> consecutive addresses (runs ~8 = full line)
        for (int i = tid; i < P1_CHUNK; i += 1024) {
            int bk = sbk[i];
            int pos = gb[bk] + (i - lb[bk]);
            cvt[pos] = stg[i];
        }
        __syncthreads();
    }
}

// ==================== pass 2: per-bucket exact placement + row_ptr build ====================

__global__ __launch_bounds__(1024) void place_kernel(const int* __restrict__ bbase,
                                                     const uint2* __restrict__ cvt,
                                                     uint2* __restrict__ cv,
                                                     int* __restrict__ row_ptr) {
    __shared__ int cur[RPB];
    __shared__ int lh[RPB];
    __shared__ int lb[RPB];
    __shared__ int sc[RPB];
    __shared__ uint2 stg[P2_CHUNK];            // 32 KB
    __shared__ unsigned short srl[P2_CHUNK];   // 8 KB
    int b = blockIdx.x, tid = threadIdx.x;
    int beg = bbase[b], end = bbase[b + 1];

    // pass A: row histogram over the whole bucket -> row_ptr + cursors
    if (tid < RPB) lh[tid] = 0;
    __syncthreads();
    for (int e = beg + tid; e < end; e += 1024)
        atomicAdd(&lh[cvt[e].x >> 19], 1);
    __syncthreads();
    int x = (tid < RPB) ? lh[tid] : 0;
    if (tid < RPB) sc[tid] = x;
    __syncthreads();
    for (int off = 1; off < RPB; off <<= 1) {
        int t = (tid < RPB && tid >= off) ? sc[tid - off] : 0;
        __syncthreads();
        if (tid < RPB) sc[tid] += t;
        __syncthreads();
    }
    if (tid < RPB) {
        int base = beg + sc[tid] - x;       // exclusive
        cur[tid] = base;
        int r = b * RPB + tid;
        if (r < N_NODES) row_ptr[r] = base;
    }
    if (b == 0 && tid == 0) row_ptr[N_NODES] = NNZ_C;
    __syncthreads();

    // pass B: chunked multi-split by row, coalesced writes at exact positions
    for (int cb = beg; cb < end; cb += P2_CHUNK) {
        int cnum = min(P2_CHUNK, end - cb);
        if (tid < RPB) lh[tid] = 0;
        __syncthreads();
        uint2 p[4]; int prl[4], prk[4];
        #pragma unroll
        for (int j = 0; j < 4; ++j) {
            int i = j * 1024 + tid;
            prl[j] = -1;
            if (i < cnum) {
                p[j] = cvt[cb + i];
                prl[j] = p[j].x >> 19;
                prk[j] = atomicAdd(&lh[prl[j]], 1);
            }
        }
        __syncthreads();
        int y = (tid < RPB) ? lh[tid] : 0;
        if (tid < RPB) sc[tid] = y;
        __syncthreads();
        for (int off = 1; off < RPB; off <<= 1) {
            int t = (tid < RPB && tid >= off) ? sc[tid - off] : 0;
            __syncthreads();
            if (tid < RPB) sc[tid] += t;
            __syncthreads();
        }
        if (tid < RPB) lb[tid] = sc[tid] - y;
        __syncthreads();
        #pragma unroll
        for (int j = 0; j < 4; ++j) {
            if (prl[j] >= 0) {
                int idx = lb[prl[j]] + prk[j];
                stg[idx] = p[j];
                srl[idx] = (unsigned short)prl[j];
            }
        }
        __syncthreads();
        for (int i = tid; i < cnum; i += 1024) {
            int rl = srl[i];
            int pos = cur[rl] + (i - lb[rl]);
            uint2 q = stg[i];
            cv[pos] = make_uint2(q.x & 0x7FFFF, q.y);   // strip rowlow -> (col, val)
        }
        __syncthreads();
        if (tid < RPB) cur[tid] += lh[tid];
        __syncthreads();
    }
}

// ==================== segmented SpMM, no atomics (unchanged) ====================

__global__ void spmm_seg_kernel(const int* __restrict__ row_ptr, const uint2* __restrict__ cv,
                                const float4* __restrict__ ego_in, float4* __restrict__ ego_out,
                                float4* __restrict__ acc, float scale, int write_ego) {
    int sub = (blockIdx.x * blockDim.x + threadIdx.x) >> 4;
    int lane = threadIdx.x & 15;
    int nsub = (gridDim.x * blockDim.x) >> 4;
    for (int r = sub; r < N_NODES; r += nsub) {
        int beg = row_ptr[r], end = row_ptr[r + 1];
        float4 s0 = make_float4(0.f, 0.f, 0.f, 0.f);
        float4 s1 = make_float4(0.f, 0.f, 0.f, 0.f);
        int e = beg;
        for (; e + 2 <= end; e += 2) {
            uint2 p0 = cv[e];
            uint2 p1 = cv[e + 1];
            float4 x0 = ego_in[p0.x * 16 + lane];
            float4 x1 = ego_in[p1.x * 16 + lane];
            float v0 = __uint_as_float(p0.y);
            float v1 = __uint_as_float(p1.y);
            s0.x += v0 * x0.x; s0.y += v0 * x0.y; s0.z += v0 * x0.z; s0.w += v0 * x0.w;
            s1.x += v1 * x1.x; s1.y += v1 * x1.y; s1.z += v1 * x1.z; s1.w += v1 * x1.w;
        }
        if (e < end) {
            uint2 p0 = cv[e];
            float4 x0 = ego_in[p0.x * 16 + lane];
            float v0 = __uint_as_float(p0.y);
            s0.x += v0 * x0.x; s0.y += v0 * x0.y; s0.z += v0 * x0.z; s0.w += v0 * x0.w;
        }
        float4 s = make_float4(s0.x + s1.x, s0.y + s1.y, s0.z + s1.z, s0.w + s1.w);
        int o = r * 16 + lane;
        float4 a = acc[o];
        a.x = (a.x + s.x) * scale;
        a.y = (a.y + s.y) * scale;
        a.z = (a.z + s.z) * scale;
        a.w = (a.w + s.w) * scale;
        acc[o] = a;
        if (write_ego) ego_out[o] = s;
    }
}

// ==================== fallback (atomic path) ====================

__global__ void zero4_kernel(float4* __restrict__ p, int n4) {
    int stride = gridDim.x * blockDim.x;
    float4 z = make_float4(0.f, 0.f, 0.f, 0.f);
    for (int i = blockIdx.x * blockDim.x + threadIdx.x; i < n4; i += stride) p[i] = z;
}

__global__ void spmm_atomic_kernel(const int* __restrict__ rows, const int* __restrict__ cols,
                                   const float* __restrict__ vals,
                                   const float* __restrict__ ego_in, float* __restrict__ ego_out) {
    int wave = (blockIdx.x * blockDim.x + threadIdx.x) >> 6;
    int lane = threadIdx.x & 63;
    int nwaves = (gridDim.x * blockDim.x) >> 6;
    for (int e = wave; e < NNZ_C; e += nwaves) {
        int r = rows[e];
        int c = cols[e];
        float v = vals[e];
        float x = ego_in[c * EMB + lane];
        atomicAdd(&ego_out[r * EMB + lane], v * x);
    }
}

__global__ void add_kernel(float4* __restrict__ acc, const float4* __restrict__ ego,
                           float scale, int n4) {
    int stride = gridDim.x * blockDim.x;
    for (int i = blockIdx.x * blockDim.x + threadIdx.x; i < n4; i += stride) {
        float4 a = acc[i];
        float4 g = ego[i];
        a.x = (a.x + g.x) * scale;
        a.y = (a.y + g.y) * scale;
        a.z = (a.z + g.z) * scale;
        a.w = (a.w + g.w) * scale;
        acc[i] = a;
    }
}

// ==================== launch ====================

extern "C" void kernel_launch(void* const* d_in, const int* in_sizes, int n_in,
                              void* d_out, int out_size, void* d_ws, size_t ws_size,
                              hipStream_t stream) {
    const float* user_emb = (const float*)d_in[0];
    const float* item_emb = (const float*)d_in[1];
    const int*   adj_rows = (const int*)d_in[2];
    const int*   adj_cols = (const int*)d_in[3];
    const float* adj_vals = (const float*)d_in[4];
    float* acc = (float*)d_out;

    const size_t egoN = (size_t)N_NODES * EMB;               // 19.2M floats
    float* ego_a = (float*)d_ws;
    float* ego_b = ego_a + egoN;

    const int total4 = N_NODES * EMB / 4;
    const int EW_BLOCKS = 4096, EW_THREADS = 256;

    // workspace layout
    uint2* cvt     = (uint2*)ego_b;                          // alias: bucket-major temp
                                                             // (NNZ*8B == egoN*4B == 76.8 MB;
                                                             //  ego_b first written after sort)
    uint2* cv      = (uint2*)(ego_b + egoN);                 // 76.8 MB final sorted (col,val)
    int* bcounts   = (int*)(cv + (size_t)NNZ_C);             // NB
    int* bbase     = bcounts + NB;                           // NB+1
    int* bcursor   = bbase + (NB + 1);                       // NB
    int* row_ptr   = bcursor + NB;                           // N_NODES+1
    size_t needed  = (size_t)((char*)(row_ptr + N_NODES + 1) - (char*)d_ws);

    if (ws_size >= needed) {
        // ---- sort edges by row: bucket multi-split + per-bucket placement ----
        zero_int_kernel<<<2, 1024, 0, stream>>>(bcounts, NB);
        bhist_kernel<<<512, 1024, 0, stream>>>(adj_rows, bcounts);
        bscan_kernel<<<1, 1024, 0, stream>>>(bcounts, bbase, bcursor);
        bin_kernel<<<256, 1024, 0, stream>>>(adj_rows, adj_cols, adj_vals, bcursor, cvt);
        place_kernel<<<NB, 1024, 0, stream>>>(bbase, cvt, cv, row_ptr);

        // ---- propagate ----
        init_kernel<<<EW_BLOCKS, EW_THREADS, 0, stream>>>(
            (const float4*)user_emb, (const float4*)item_emb,
            (float4*)ego_a, (float4*)acc);

        spmm_seg_kernel<<<2048, 256, 0, stream>>>(row_ptr, cv, (const float4*)ego_a,
                                                  (float4*)ego_b, (float4*)acc, 1.0f, 1);
        spmm_seg_kernel<<<2048, 256, 0, stream>>>(row_ptr, cv, (const float4*)ego_b,
                                                  (float4*)ego_a, (float4*)acc, 1.0f, 1);
        spmm_seg_kernel<<<2048, 256, 0, stream>>>(row_ptr, cv, (const float4*)ego_a,
                                                  (float4*)ego_b, (float4*)acc, 0.25f, 0);
    } else {
        // ---- fallback: atomic COO path ----
        init_kernel<<<EW_BLOCKS, EW_THREADS, 0, stream>>>(
            (const float4*)user_emb, (const float4*)item_emb,
            (float4*)ego_a, (float4*)acc);
        float* ego_in = ego_a;
        float* ego_out = ego_b;
        for (int layer = 0; layer < 3; ++layer) {
            zero4_kernel<<<EW_BLOCKS, EW_THREADS, 0, stream>>>((float4*)ego_out, total4);
            spmm_atomic_kernel<<<4096, 256, 0, stream>>>(
                adj_rows, adj_cols, adj_vals, ego_in, ego_out);
            float scale = (layer == 2) ? 0.25f : 1.0f;
            add_kernel<<<EW_BLOCKS, EW_THREADS, 0, stream>>>(
                (float4*)acc, (const float4*)ego_out, scale, total4);
            float* t = ego_in; ego_in = ego_out; ego_out = t;
        }
    }
}